// Round 15
// baseline (63.433 us; speedup 1.0000x reference)
//
#include <hip/hip_runtime.h>
#include <hip/hip_bf16.h>

// Problem constants
#define NA 32      // agents per graph
#define NACT 64    // actions
#define NIN 128    // in_dim
#define NOUT 128   // out_dim
#define NB 256     // graphs
// Inputs f32. Outputs f32: obs_final [8192,32,192] then w_out [8192,32,1].
//
// Round 15: ONE dispatch, 8448 blocks x 256 thr.
//   bid <  256 : graph block  — qk (w stays in LDS) + pipelined z for all
//                32 rows of graph bid (8 rows per wave, rolling A/B noise).
//   bid >= 256 : obs-copy block for dst row bid-256 (134 MB write stream,
//                runs concurrently with graph-block compute from t~0).
// No w round-trip, no inter-dispatch barrier, 2 __syncthreads total.

__global__ __launch_bounds__(256) void fused_one(
    const float* __restrict__ h,
    const float* __restrict__ Wk, const float* __restrict__ bk,
    const float* __restrict__ Wq, const float* __restrict__ bq,
    const float* __restrict__ policies, const float* __restrict__ actions,
    const float* __restrict__ obs, const float* __restrict__ noise,
    float* __restrict__ out, float* __restrict__ w_out)
{
    __shared__ float sh[NA][NIN];         // 16 KB
    __shared__ float sK[NA][NOUT + 4];    // 16.5 KB
    __shared__ float sQ[NA][NOUT + 4];    // 16.5 KB
    __shared__ float sw[NA][NA];          // 4 KB
    __shared__ float spi[2048];           // 8 KB
    __shared__ float sac[2048];           // 8 KB   (69.5 KB total)

    const int bid = blockIdx.x;
    const int tid = threadIdx.x;

    if (bid >= NB) {
        // ---- obs-copy block: dst row gr = bid-256
        const int gr = bid - NB;
        const int b  = gr >> 5;
        const float4* so4 = reinterpret_cast<const float4*>(obs + (size_t)b * NA * NIN);
        float4* out4 = reinterpret_cast<float4*>(out) + (size_t)gr * 1536;
#pragma unroll
        for (int k = 0; k < 4; ++k) {
            const int m = tid + 256 * k;            // 0..1023
            out4[(m >> 5) * 48 + (m & 31)] = so4[m];
        }
        return;
    }

    // ================= graph block for graph b =================
    const int b = bid;

    // ---- stage h + pi/act
    {
        const float4* hs = reinterpret_cast<const float4*>(h + (size_t)b * NA * NIN);
        float4* shl = reinterpret_cast<float4*>(&sh[0][0]);
#pragma unroll
        for (int k = 0; k < 4; ++k) { const int m = tid + 256 * k; shl[m] = hs[m]; }
        const float4* ps = reinterpret_cast<const float4*>(policies + (size_t)b * 2048);
        const float4* as = reinterpret_cast<const float4*>(actions  + (size_t)b * 2048);
        float4* pd = reinterpret_cast<float4*>(spi);
        float4* ad = reinterpret_cast<float4*>(sac);
        pd[tid] = ps[tid]; pd[tid + 256] = ps[tid + 256];
        ad[tid] = as[tid]; ad[tid + 256] = as[tid + 256];
    }
    __syncthreads();

    // ---- projection: txg = tid&31 (4 out-dims), ty = tid>>5 (4 nodes)
    {
        const int txg = tid & 31;
        const int ty  = tid >> 5;
        float4 kacc[4], qacc[4];
        const float4 bk4 = *reinterpret_cast<const float4*>(bk + txg * 4);
        const float4 bq4 = *reinterpret_cast<const float4*>(bq + txg * 4);
#pragma unroll
        for (int s = 0; s < 4; ++s) { kacc[s] = bk4; qacc[s] = bq4; }

        for (int rr4 = 0; rr4 < NIN; rr4 += 4) {
            float4 wk[4], wq[4];
#pragma unroll
            for (int rr = 0; rr < 4; ++rr) {
                wk[rr] = *reinterpret_cast<const float4*>(Wk + (size_t)(rr4 + rr) * NOUT + txg * 4);
                wq[rr] = *reinterpret_cast<const float4*>(Wq + (size_t)(rr4 + rr) * NOUT + txg * 4);
            }
#pragma unroll
            for (int s = 0; s < 4; ++s) {
                const float4 hv = *reinterpret_cast<const float4*>(&sh[ty * 4 + s][rr4]);
                kacc[s].x = fmaf(hv.x, wk[0].x, fmaf(hv.y, wk[1].x, fmaf(hv.z, wk[2].x, fmaf(hv.w, wk[3].x, kacc[s].x))));
                kacc[s].y = fmaf(hv.x, wk[0].y, fmaf(hv.y, wk[1].y, fmaf(hv.z, wk[2].y, fmaf(hv.w, wk[3].y, kacc[s].y))));
                kacc[s].z = fmaf(hv.x, wk[0].z, fmaf(hv.y, wk[1].z, fmaf(hv.z, wk[2].z, fmaf(hv.w, wk[3].z, kacc[s].z))));
                kacc[s].w = fmaf(hv.x, wk[0].w, fmaf(hv.y, wk[1].w, fmaf(hv.z, wk[2].w, fmaf(hv.w, wk[3].w, kacc[s].w))));
                qacc[s].x = fmaf(hv.x, wq[0].x, fmaf(hv.y, wq[1].x, fmaf(hv.z, wq[2].x, fmaf(hv.w, wq[3].x, qacc[s].x))));
                qacc[s].y = fmaf(hv.x, wq[0].y, fmaf(hv.y, wq[1].y, fmaf(hv.z, wq[2].y, fmaf(hv.w, wq[3].y, qacc[s].y))));
                qacc[s].z = fmaf(hv.x, wq[0].z, fmaf(hv.y, wq[1].z, fmaf(hv.z, wq[2].z, fmaf(hv.w, wq[3].z, qacc[s].z))));
                qacc[s].w = fmaf(hv.x, wq[0].w, fmaf(hv.y, wq[1].w, fmaf(hv.z, wq[2].w, fmaf(hv.w, wq[3].w, qacc[s].w))));
            }
        }
#pragma unroll
        for (int s = 0; s < 4; ++s) {
            *reinterpret_cast<float4*>(&sK[ty * 4 + s][txg * 4]) = kacc[s];
            *reinterpret_cast<float4*>(&sQ[ty * 4 + s][txg * 4]) = qacc[s];
        }
    }
    __syncthreads();

    // ---- scores + softmax: i = tid>>3 (dst row), jg = tid&7 (4 src j's).
    // Wave wv covers exactly i in [wv*8, wv*8+8) -> sw rows are wave-local,
    // so the z phase below needs NO barrier.
    {
        const int i  = tid >> 3;
        const int jg = tid & 7;
        float sc[4] = {0.f, 0.f, 0.f, 0.f};
        for (int rr4 = 0; rr4 < NOUT; rr4 += 4) {
            const float4 qv = *reinterpret_cast<const float4*>(&sQ[i][rr4]);
#pragma unroll
            for (int jj = 0; jj < 4; ++jj) {
                const float4 kv = *reinterpret_cast<const float4*>(&sK[jg * 4 + jj][rr4]);
                sc[jj] = fmaf(qv.x, kv.x, fmaf(qv.y, kv.y, fmaf(qv.z, kv.z, fmaf(qv.w, kv.w, sc[jj]))));
            }
        }
#pragma unroll
        for (int jj = 0; jj < 4; ++jj) sc[jj] *= 0.08838834764831845f;  // 1/sqrt(128)

        float m = fmaxf(fmaxf(sc[0], sc[1]), fmaxf(sc[2], sc[3]));
        m = fmaxf(m, __shfl_xor(m, 1));
        m = fmaxf(m, __shfl_xor(m, 2));
        m = fmaxf(m, __shfl_xor(m, 4));
        float e[4];
#pragma unroll
        for (int jj = 0; jj < 4; ++jj) e[jj] = __expf(sc[jj] - m);
        float ssum = e[0] + e[1] + e[2] + e[3];
        ssum += __shfl_xor(ssum, 1);
        ssum += __shfl_xor(ssum, 2);
        ssum += __shfl_xor(ssum, 4);
        const float inv = 1.0f / ssum;

        const float4 w4 = make_float4(e[0] * inv, e[1] * inv, e[2] * inv, e[3] * inv);
        *reinterpret_cast<float4*>(&sw[i][jg * 4]) = w4;
        *reinterpret_cast<float4*>(w_out + ((size_t)b * NA + i) * NA + jg * 4) = w4;
    }

    // ---- z phase: wave wv owns rows i0..i0+7; rolling A/B noise prefetch
    const int wv   = tid >> 6;
    const int lane = tid & 63;
    const int qq   = lane >> 4;   // t-octet 0..3
    const int cg   = lane & 15;   // col group (4 floats)
    const int c0   = cg * 4;
    const int i0   = wv * 8;
    const size_t gr0 = (size_t)b * NA + i0;
    const float* nz = noise + gr0 * 2048 + qq * 512 + c0;
    float4* outg = reinterpret_cast<float4*>(out) + gr0 * 1536;

    auto zrow = [&](const float4* BUF, int r) {
        const int i = i0 + r;
        float S0 = 0.f, S1 = 0.f, S2 = 0.f, S3 = 0.f;
        float y[8][4];
#pragma unroll
        for (int tt = 0; tt < 8; ++tt) {
            const int t = qq * 8 + tt;
            const float wt = sw[i][t];
            const float4 p4 = *reinterpret_cast<const float4*>(&spi[t * 64 + c0]);
            const float4 a4 = *reinterpret_cast<const float4*>(&sac[t * 64 + c0]);
            const float4 n4 = BUF[tt];
            float z;
            z = fmaf(wt, a4.x - p4.x, p4.x) + n4.x; S0 += z; y[tt][0] = p4.x - z;
            z = fmaf(wt, a4.y - p4.y, p4.y) + n4.y; S1 += z; y[tt][1] = p4.y - z;
            z = fmaf(wt, a4.z - p4.z, p4.z) + n4.z; S2 += z; y[tt][2] = p4.z - z;
            z = fmaf(wt, a4.w - p4.w, p4.w) + n4.w; S3 += z; y[tt][3] = p4.w - z;
        }
        S0 += __shfl_xor(S0, 16); S0 += __shfl_xor(S0, 32);
        S1 += __shfl_xor(S1, 16); S1 += __shfl_xor(S1, 32);
        S2 += __shfl_xor(S2, 16); S2 += __shfl_xor(S2, 32);
        S3 += __shfl_xor(S3, 16); S3 += __shfl_xor(S3, 32);

        float4* o4 = outg + (size_t)r * 1536;
#pragma unroll
        for (int tt = 0; tt < 8; ++tt) {
            const int t = qq * 8 + tt;
            float4 o;
            o.x = (S0 + y[tt][0]) * (1.0f / NA);
            o.y = (S1 + y[tt][1]) * (1.0f / NA);
            o.z = (S2 + y[tt][2]) * (1.0f / NA);
            o.w = (S3 + y[tt][3]) * (1.0f / NA);
            o4[t * 48 + 32 + cg] = o;
        }
    };

    float4 A[8], B[8];
#pragma unroll
    for (int tt = 0; tt < 8; ++tt) A[tt] = *reinterpret_cast<const float4*>(nz + tt * 64);

#pragma unroll
    for (int rp = 0; rp < 8; rp += 2) {
        if (rp + 1 < 8) {
#pragma unroll
            for (int tt = 0; tt < 8; ++tt)
                B[tt] = *reinterpret_cast<const float4*>(nz + (size_t)(rp + 1) * 2048 + tt * 64);
        }
        zrow(A, rp);
        if (rp + 2 < 8) {
#pragma unroll
            for (int tt = 0; tt < 8; ++tt)
                A[tt] = *reinterpret_cast<const float4*>(nz + (size_t)(rp + 2) * 2048 + tt * 64);
        }
        if (rp + 1 < 8) zrow(B, rp + 1);
    }
}

extern "C" void kernel_launch(void* const* d_in, const int* in_sizes, int n_in,
                              void* d_out, int out_size, void* d_ws, size_t ws_size,
                              hipStream_t stream) {
    const float* h        = (const float*)d_in[0];
    const float* policies = (const float*)d_in[1];
    const float* actions  = (const float*)d_in[2];
    const float* obs_proc = (const float*)d_in[3];
    const float* noise    = (const float*)d_in[4];
    const float* Wk       = (const float*)d_in[5];
    const float* bk       = (const float*)d_in[6];
    const float* Wq       = (const float*)d_in[7];
    const float* bq       = (const float*)d_in[8];

    float* out = (float*)d_out;
    float* obs_final = out;                                      // [8192,32,192]
    float* w_out = out + (size_t)NB * NA * NA * (NIN + NACT);    // [8192,32,1]

    fused_one<<<NB + NB * NA, 256, 0, stream>>>(h, Wk, bk, Wq, bq,
                                                policies, actions, obs_proc,
                                                noise, obs_final, w_out);
}

// Round 18
// 59.191 us; speedup vs baseline: 1.0717x; 1.0717x over previous
//
#include <hip/hip_runtime.h>
#include <hip/hip_bf16.h>

// Problem constants
#define NA 32      // agents per graph
#define NACT 64    // actions
#define NIN 128    // in_dim
#define NOUT 128   // out_dim
#define NB 256     // graphs
// Inputs f32. Outputs f32: obs_final [8192,32,192] then w_out [8192,32,1].
//
// Round 18 = Round 17 resubmitted (infra drop): R14 base (61.0 us) +
//   - NT stores for the 201 MB obs_final stream (don't thrash L2)
//   - NT loads for noise (read-once)
//   - XCD-affinity swizzles: same-graph blocks -> same XCD

typedef float floatx4 __attribute__((ext_vector_type(4)));

__device__ __forceinline__ void nt_store4(float4* p, float4 v) {
    floatx4 nv = {v.x, v.y, v.z, v.w};
    __builtin_nontemporal_store(nv, reinterpret_cast<floatx4*>(p));
}
__device__ __forceinline__ float4 nt_load4(const float4* p) {
    floatx4 nv = __builtin_nontemporal_load(
        reinterpret_cast<const floatx4*>(p));
    return make_float4(nv.x, nv.y, nv.z, nv.w);
}

// ---------------------------------------------------------------------------
// K1: 8448 blocks x 256.  bid<256: qk -> w_out.  bid>=256: obs-copy row,
// XCD-swizzled so each graph's 32 rows are on one XCD.
// ---------------------------------------------------------------------------
__global__ __launch_bounds__(256) void k1_qk_obscopy(
    const float* __restrict__ h,
    const float* __restrict__ Wk, const float* __restrict__ bk,
    const float* __restrict__ Wq, const float* __restrict__ bq,
    const float* __restrict__ obs,
    float* __restrict__ out, float* __restrict__ w_out)
{
    __shared__ float sh[NA][NIN];         // 16 KB
    __shared__ float sK[NA][NOUT + 4];    // 16.5 KB
    __shared__ float sQ[NA][NOUT + 4];    // 16.5 KB

    const int bid = blockIdx.x;
    const int tid = threadIdx.x;

    if (bid >= NB) {
        // swizzle: xcd = x&7 handles graphs b == xcd (mod 8)
        const int x   = bid - NB;
        const int xcd = x & 7;
        const int idx = x >> 3;                       // 0..1023
        const int gr  = xcd * 32 + (idx >> 5) * 256 + (idx & 31);
        const int b   = gr >> 5;
        const float4* so4 = reinterpret_cast<const float4*>(obs + (size_t)b * NA * NIN);
        float4* out4 = reinterpret_cast<float4*>(out) + (size_t)gr * 1536;
#pragma unroll
        for (int kk = 0; kk < 4; ++kk) {
            const int m = tid + 256 * kk;             // 0..1023
            nt_store4(&out4[(m >> 5) * 48 + (m & 31)], so4[m]);
        }
        return;
    }

    // ---- qk block for graph g
    const int g = bid;

    {
        const float4* hs = reinterpret_cast<const float4*>(h + (size_t)g * NA * NIN);
        float4* shl = reinterpret_cast<float4*>(&sh[0][0]);
#pragma unroll
        for (int kk = 0; kk < 4; ++kk) { const int m = tid + 256 * kk; shl[m] = hs[m]; }
    }
    __syncthreads();

    // projection: txg = tid&31 (4 out-dims), ty = tid>>5 (4 nodes)
    {
        const int txg = tid & 31;
        const int ty  = tid >> 5;
        float4 kacc[4], qacc[4];
        const float4 bk4 = *reinterpret_cast<const float4*>(bk + txg * 4);
        const float4 bq4 = *reinterpret_cast<const float4*>(bq + txg * 4);
#pragma unroll
        for (int s = 0; s < 4; ++s) { kacc[s] = bk4; qacc[s] = bq4; }

        for (int rr4 = 0; rr4 < NIN; rr4 += 4) {
            float4 wk[4], wq[4];
#pragma unroll
            for (int rr = 0; rr < 4; ++rr) {
                wk[rr] = *reinterpret_cast<const float4*>(Wk + (size_t)(rr4 + rr) * NOUT + txg * 4);
                wq[rr] = *reinterpret_cast<const float4*>(Wq + (size_t)(rr4 + rr) * NOUT + txg * 4);
            }
#pragma unroll
            for (int s = 0; s < 4; ++s) {
                const float4 hv = *reinterpret_cast<const float4*>(&sh[ty * 4 + s][rr4]);
                kacc[s].x = fmaf(hv.x, wk[0].x, fmaf(hv.y, wk[1].x, fmaf(hv.z, wk[2].x, fmaf(hv.w, wk[3].x, kacc[s].x))));
                kacc[s].y = fmaf(hv.x, wk[0].y, fmaf(hv.y, wk[1].y, fmaf(hv.z, wk[2].y, fmaf(hv.w, wk[3].y, kacc[s].y))));
                kacc[s].z = fmaf(hv.x, wk[0].z, fmaf(hv.y, wk[1].z, fmaf(hv.z, wk[2].z, fmaf(hv.w, wk[3].z, kacc[s].z))));
                kacc[s].w = fmaf(hv.x, wk[0].w, fmaf(hv.y, wk[1].w, fmaf(hv.z, wk[2].w, fmaf(hv.w, wk[3].w, kacc[s].w))));
                qacc[s].x = fmaf(hv.x, wq[0].x, fmaf(hv.y, wq[1].x, fmaf(hv.z, wq[2].x, fmaf(hv.w, wq[3].x, qacc[s].x))));
                qacc[s].y = fmaf(hv.x, wq[0].y, fmaf(hv.y, wq[1].y, fmaf(hv.z, wq[2].y, fmaf(hv.w, wq[3].y, qacc[s].y))));
                qacc[s].z = fmaf(hv.x, wq[0].z, fmaf(hv.y, wq[1].z, fmaf(hv.z, wq[2].z, fmaf(hv.w, wq[3].z, qacc[s].z))));
                qacc[s].w = fmaf(hv.x, wq[0].w, fmaf(hv.y, wq[1].w, fmaf(hv.z, wq[2].w, fmaf(hv.w, wq[3].w, qacc[s].w))));
            }
        }
#pragma unroll
        for (int s = 0; s < 4; ++s) {
            *reinterpret_cast<float4*>(&sK[ty * 4 + s][txg * 4]) = kacc[s];
            *reinterpret_cast<float4*>(&sQ[ty * 4 + s][txg * 4]) = qacc[s];
        }
    }
    __syncthreads();

    // scores + softmax: i = tid>>3 (dst row), jg = tid&7 (4 src j's)
    {
        const int i  = tid >> 3;
        const int jg = tid & 7;
        float sc[4] = {0.f, 0.f, 0.f, 0.f};
        for (int rr4 = 0; rr4 < NOUT; rr4 += 4) {
            const float4 qv = *reinterpret_cast<const float4*>(&sQ[i][rr4]);
#pragma unroll
            for (int jj = 0; jj < 4; ++jj) {
                const float4 kv = *reinterpret_cast<const float4*>(&sK[jg * 4 + jj][rr4]);
                sc[jj] = fmaf(qv.x, kv.x, fmaf(qv.y, kv.y, fmaf(qv.z, kv.z, fmaf(qv.w, kv.w, sc[jj]))));
            }
        }
#pragma unroll
        for (int jj = 0; jj < 4; ++jj) sc[jj] *= 0.08838834764831845f;  // 1/sqrt(128)

        float m = fmaxf(fmaxf(sc[0], sc[1]), fmaxf(sc[2], sc[3]));
        m = fmaxf(m, __shfl_xor(m, 1));
        m = fmaxf(m, __shfl_xor(m, 2));
        m = fmaxf(m, __shfl_xor(m, 4));
        float e[4];
#pragma unroll
        for (int jj = 0; jj < 4; ++jj) e[jj] = __expf(sc[jj] - m);
        float ssum = e[0] + e[1] + e[2] + e[3];
        ssum += __shfl_xor(ssum, 1);
        ssum += __shfl_xor(ssum, 2);
        ssum += __shfl_xor(ssum, 4);
        const float inv = 1.0f / ssum;

        *reinterpret_cast<float4*>(w_out + ((size_t)g * NA + i) * NA + jg * 4) =
            make_float4(e[0] * inv, e[1] * inv, e[2] * inv, e[3] * inv);
    }
}

// ---------------------------------------------------------------------------
// K2: pipelined z_mix, XCD-swizzled. grid=1024, block=256 (4 waves).
// Block -> (graph b = xcd + 8k, oct s): rows b*32 + s*8 .. +8. Wave owns 2
// rows, both rows' noise loads (NT) issued up front.
// ---------------------------------------------------------------------------
__global__ __launch_bounds__(256) void k2_zmix(
    const float* __restrict__ policies, const float* __restrict__ actions,
    const float* __restrict__ noise, const float* __restrict__ w_in,
    float* __restrict__ out)
{
    __shared__ float spi[2048];   // 8 KB
    __shared__ float sac[2048];   // 8 KB
    __shared__ float sww[256];    // 1 KB

    const int blk  = blockIdx.x;  // 0..1023
    const int xcd  = blk & 7;
    const int rest = blk >> 3;
    const int kk2  = rest >> 2;
    const int s    = rest & 3;
    const int b    = xcd + 8 * kk2;   // graph
    const int row0 = b * NA + s * 8;  // first of this block's 8 rows
    const int tid  = threadIdx.x;

    {
        const float4* ps = reinterpret_cast<const float4*>(policies + (size_t)b * 2048);
        const float4* as = reinterpret_cast<const float4*>(actions  + (size_t)b * 2048);
        float4* pd = reinterpret_cast<float4*>(spi);
        float4* ad = reinterpret_cast<float4*>(sac);
        pd[tid] = ps[tid]; pd[tid + 256] = ps[tid + 256];
        ad[tid] = as[tid]; ad[tid + 256] = as[tid + 256];
        sww[tid] = w_in[(size_t)row0 * NA + tid];
    }
    __syncthreads();

    const int wv   = tid >> 6;
    const int lane = tid & 63;
    const int qq   = lane >> 4;   // t-octet 0..3
    const int cg   = lane & 15;   // col group (4 floats)
    const int c0   = cg * 4;
    const int lr0  = wv * 2;                     // local rows lr0, lr0+1
    const size_t r0 = (size_t)row0 + lr0;        // global dst rows r0, r0+1

    const float* nz0 = noise + r0 * 2048 + qq * 512 + c0;
    const float* nz1 = nz0 + 2048;
    float4 A[8], B[8];
#pragma unroll
    for (int tt = 0; tt < 8; ++tt) A[tt] = nt_load4(reinterpret_cast<const float4*>(nz0 + tt * 64));
#pragma unroll
    for (int tt = 0; tt < 8; ++tt) B[tt] = nt_load4(reinterpret_cast<const float4*>(nz1 + tt * 64));

    auto do_row = [&](const float4* BUF, int lr, size_t gr) {
        const float* wr = &sww[lr * 32];
        float S0 = 0.f, S1 = 0.f, S2 = 0.f, S3 = 0.f;
        float y[8][4];
#pragma unroll
        for (int tt = 0; tt < 8; ++tt) {
            const int t = qq * 8 + tt;
            const float wt = wr[t];
            const float4 p4 = *reinterpret_cast<const float4*>(&spi[t * 64 + c0]);
            const float4 a4 = *reinterpret_cast<const float4*>(&sac[t * 64 + c0]);
            const float4 n4 = BUF[tt];
            float z;
            z = fmaf(wt, a4.x - p4.x, p4.x) + n4.x; S0 += z; y[tt][0] = p4.x - z;
            z = fmaf(wt, a4.y - p4.y, p4.y) + n4.y; S1 += z; y[tt][1] = p4.y - z;
            z = fmaf(wt, a4.z - p4.z, p4.z) + n4.z; S2 += z; y[tt][2] = p4.z - z;
            z = fmaf(wt, a4.w - p4.w, p4.w) + n4.w; S3 += z; y[tt][3] = p4.w - z;
        }
        S0 += __shfl_xor(S0, 16); S0 += __shfl_xor(S0, 32);
        S1 += __shfl_xor(S1, 16); S1 += __shfl_xor(S1, 32);
        S2 += __shfl_xor(S2, 16); S2 += __shfl_xor(S2, 32);
        S3 += __shfl_xor(S3, 16); S3 += __shfl_xor(S3, 32);

        float4* out4 = reinterpret_cast<float4*>(out) + gr * 1536;
#pragma unroll
        for (int tt = 0; tt < 8; ++tt) {
            const int t = qq * 8 + tt;
            float4 o;
            o.x = (S0 + y[tt][0]) * (1.0f / NA);
            o.y = (S1 + y[tt][1]) * (1.0f / NA);
            o.z = (S2 + y[tt][2]) * (1.0f / NA);
            o.w = (S3 + y[tt][3]) * (1.0f / NA);
            nt_store4(&out4[t * 48 + 32 + cg], o);
        }
    };

    do_row(A, lr0, r0);
    do_row(B, lr0 + 1, r0 + 1);
}

extern "C" void kernel_launch(void* const* d_in, const int* in_sizes, int n_in,
                              void* d_out, int out_size, void* d_ws, size_t ws_size,
                              hipStream_t stream) {
    const float* h        = (const float*)d_in[0];
    const float* policies = (const float*)d_in[1];
    const float* actions  = (const float*)d_in[2];
    const float* obs_proc = (const float*)d_in[3];
    const float* noise    = (const float*)d_in[4];
    const float* Wk       = (const float*)d_in[5];
    const float* bk       = (const float*)d_in[6];
    const float* Wq       = (const float*)d_in[7];
    const float* bq       = (const float*)d_in[8];

    float* out = (float*)d_out;
    float* obs_final = out;                                      // [8192,32,192]
    float* w_out = out + (size_t)NB * NA * NA * (NIN + NACT);    // [8192,32,1]

    k1_qk_obscopy<<<NB + NB * NA, 256, 0, stream>>>(h, Wk, bk, Wq, bq, obs_proc,
                                                    obs_final, w_out);
    k2_zmix<<<1024, 256, 0, stream>>>(policies, actions, noise, w_out, obs_final);
}